// Round 10
// baseline (18045.172 us; speedup 1.0000x reference)
//
#include <hip/hip_runtime.h>

typedef _Float16 f16;
typedef __attribute__((ext_vector_type(8))) _Float16 f16x8;
typedef __attribute__((ext_vector_type(4))) float f32x4;

#define NBATCH 1024
#define NH 1024
#define NT 336
#define NDFF 7
#define NQ 9
#define K0 1088   /* 64 (x padded) + 1024 (h0) */
#define K1 2048   /* 1024 (h0_new) + 1024 (h1) */
#define OUTSTRIDE (NT * NQ)
#define XAOFF 131072   /* dedicated 16KB x-tile A region (layer 0) */

__device__ __forceinline__ float sigf(float x) { return 1.0f / (1.0f + __expf(-x)); }
__device__ __forceinline__ float tanhfast(float x) { return 1.0f - 2.0f / (__expf(2.0f * x) + 1.0f); }

// gll kept ONLY for the tiny L0 t0-B prologue stage (4 instrs, once/kernel)
__device__ __forceinline__ void gll(const void* g, void* l) {
  __builtin_amdgcn_global_load_lds((const __attribute__((address_space(1))) void*)g,
                                   (__attribute__((address_space(3))) void*)l, 16, 0, 0);
}

// ---------------------------------------------------------------------------
// Weight pack: rows permuted so LDS B-tile row p: gate=(p>>4)&3,
// hcol_local=(p>>6)*16+(p&15) -> MFMA n-index == gate.
// k pre-swizzled per 64-col chunk: dst_k = (k&~63)|((k&63)^((p&7)<<3)).
// ---------------------------------------------------------------------------
__global__ void pack_w0(const float* __restrict__ Wih0, const float* __restrict__ Whh0,
                        f16* __restrict__ Wp0) {
  const int idx = blockIdx.x * 256 + threadIdx.x;  // exactly 4096*K0
  const int pr = idx / K0;
  const int dk = idx - pr * K0;
  const int cb = pr >> 7, p = pr & 127;
  const int gate = (p >> 4) & 3;
  const int hl = ((p >> 6) << 4) | (p & 15);
  const int j = (gate << 10) + (cb << 5) + hl;
  const int sk = (dk & ~63) | ((dk & 63) ^ ((p & 7) << 3));
  float v;
  if (sk < 8) v = Wih0[j * 8 + sk];
  else if (sk < 64) v = 0.0f;
  else v = Whh0[(size_t)j * NH + (sk - 64)];
  Wp0[idx] = (f16)v;
}

__global__ void pack_w1(const float* __restrict__ Wih1, const float* __restrict__ Whh1,
                        f16* __restrict__ Wp1) {
  const int idx = blockIdx.x * 256 + threadIdx.x;  // exactly 4096*2048
  const int pr = idx >> 11;
  const int dk = idx & 2047;
  const int cb = pr >> 7, p = pr & 127;
  const int gate = (p >> 4) & 3;
  const int hl = ((p >> 6) << 4) | (p & 15);
  const int j = (gate << 10) + (cb << 5) + hl;
  const int sk = (dk & ~63) | ((dk & 63) ^ ((p & 7) << 3));
  const float v = (sk < 1024) ? Wih1[(size_t)j * NH + sk]
                              : Whh1[(size_t)j * NH + (sk - 1024)];
  Wp1[idx] = (f16)v;
}

__global__ void pack_bias(const float* __restrict__ a0, const float* __restrict__ b0,
                          const float* __restrict__ a1, const float* __restrict__ b1,
                          float* __restrict__ bias0, float* __restrict__ bias1) {
  const int j = blockIdx.x * 256 + threadIdx.x;
  if (j < 4096) { bias0[j] = a0[j] + b0[j]; bias1[j] = a1[j] + b1[j]; }
}

// h fp16 pre-swizzled (chunk swizzle keyed by row&7)
__global__ void init_h(const float* __restrict__ h_in,
                       f16* __restrict__ h0, f16* __restrict__ h1) {
  const int idx = blockIdx.x * 256 + threadIdx.x;  // exactly 2*1024*1024
  const int l = idx >> 20;
  const int rc = idx & 1048575;
  const int row = rc >> 10;
  const int dk = idx & 1023;
  const int sk = (dk & ~63) | ((dk & 63) ^ ((row & 7) << 3));
  const float hv = h_in[((size_t)l << 20) + ((size_t)row << 10) + sk];
  if (l == 0) h0[rc] = (f16)hv;
  else        h1[rc] = (f16)hv;
}

// c packed so each thread's 16 values are lane-coalesced:
// cpk[l][ ((rb*32+cb)*4+wv)*1024 + j*64 + ln ], j = m*4+r
__global__ void init_c(const float* __restrict__ c_in, float* __restrict__ c0p,
                       float* __restrict__ c1p) {
  const int idx = blockIdx.x * 256 + threadIdx.x;  // exactly 2*1024*1024
  const int l = idx >> 20;
  const int rem = idx & 1048575;
  const int ln = rem & 63;
  const int j = (rem >> 6) & 15;
  const int wv = (rem >> 10) & 3;
  const int cb = (rem >> 12) & 31;
  const int rb = rem >> 17;
  const int row = rb * 128 + (wv >> 1) * 64 + (j >> 2) * 16 + ((ln >> 4) & 3) * 4 + (j & 3);
  const int col = cb * 32 + (wv & 1) * 16 + (ln & 15);
  const float v = c_in[((size_t)l << 20) + ((size_t)row << 10) + col];
  if (l == 0) c0p[rem] = v; else c1p[rem] = v;
}

__global__ void final_y(const float* __restrict__ ypartT, const float* __restrict__ bout,
                        float* __restrict__ dout) {
  const int idx = blockIdx.x * 256 + threadIdx.x;  // exactly 9216
  const int row = idx & 1023;
  const int q = idx >> 10;
  float s = bout[q];
#pragma unroll
  for (int nb2 = 0; nb2 < 32; ++nb2) s += ypartT[(((q << 5) + nb2) << 10) + row];
  dout[(size_t)row * OUTSTRIDE + 335 * NQ + q] = s;
}

// ---------------------------------------------------------------------------
// Step kernel, BK=128, stage-ahead-1, REGISTER STAGING (round 9 -> 10):
// global_load_lds processes ~1 lane/cy (~58 cy/KB measured across r2/r9) —
// replace with global_load_dwordx4 -> VGPR -> ds_write_b128 which coalesces
// at L2 BW (~18 cy/KB) + LDS write (8 cy/KB).
// Schedule per iter i:
//   issue 16 loads (t_{i+1}) -> compute t_i (slot i&1) -> [auto vmcnt waits]
//   ds_write t_{i+1} into slot (i+1)&1 (freed at iter i-1's end barrier)
//   -> lgkmcnt(0) -> s_barrier (publishes t_{i+1}, frees slot i&1).
// Loads overlap the whole compute (~700cy > L2/L3 latency).
// Coherence: all plain loads/stores — kernel boundaries order everything.
// ---------------------------------------------------------------------------
template <int L>
__global__ __launch_bounds__(256, 1) void step_kernel(
    const f16* __restrict__ Wp, const float* __restrict__ bias,
    const f16* __restrict__ hA0, const f16* __restrict__ hA1,
    f16* __restrict__ hout, float* __restrict__ cpk,
    const float* __restrict__ ff, const float* __restrict__ inpy,
    float* __restrict__ ypartT, const float* __restrict__ Wout,
    const float* __restrict__ bout, float* __restrict__ dout, int t) {
  constexpr int KDIM = L ? K1 : K0;
  constexpr int NTILE = L ? 16 : 9;
  __shared__ __align__(16) unsigned char lds8[147456];  // 2x64KB + 16KB xA

  const int tid = threadIdx.x;
  const int wv = tid >> 6;
  const int ln = tid & 63;
  const int wr = wv >> 1, wc = wv & 1;
  const int blk = blockIdx.x;
  const int rb = (blk >> 3) & 7;
  const int cb = (blk & 7) * 4 + (blk >> 6);   // XCD-striped colblocks
  const int row0 = rb * 128;
  const int hcol0 = cb * 32;

  const int lanerow = ln & 15;
  const int xm = (ln & 7) << 4;
  const int kgrp = (ln >> 4) << 4;
  const int hcol = hcol0 + wc * 16 + lanerow;

  // ---- register staging: load tile j into regs / write regs to slot ----
  f16x8 ra[8], rb8[8];
  auto loadRegs = [&](int j) {
    const f16* hsrc; int koff, wk0;
    if (L) {
      if (j < 8) { hsrc = hA0; koff = j * 128; } else { hsrc = hA1; koff = (j - 8) * 128; }
      wk0 = j * 128;
    } else {
      hsrc = hA0; koff = (j - 1) * 128; wk0 = 64 + (j - 1) * 128;
    }
#pragma unroll
    for (int ii = 0; ii < 8; ++ii) {
      const int ci = wv * 8 + ii;
      const int r = ci * 4 + (ln >> 4);                 // 4 rows/instr, 256B rows
      ra[ii] = *(const f16x8*)(hsrc + (((size_t)(row0 + r)) << 10) + koff + (ln & 15) * 8);
    }
#pragma unroll
    for (int ii = 0; ii < 8; ++ii) {
      const int ci = wv * 8 + ii;
      const int pr = ci * 4 + (ln >> 4);
      rb8[ii] = *(const f16x8*)(Wp + (size_t)(cb * 128 + pr) * KDIM + wk0 + (ln & 15) * 8);
    }
  };
  auto writeLDS = [&](int slot) {
    unsigned char* sb = lds8 + slot * 65536;
#pragma unroll
    for (int ii = 0; ii < 8; ++ii) {
      const int ci = wv * 8 + ii;
      *(f16x8*)(sb + ci * 1024 + ln * 16) = ra[ii];
    }
#pragma unroll
    for (int ii = 0; ii < 8; ++ii) {
      const int ci = wv * 8 + ii;
      *(f16x8*)(sb + 32768 + ci * 1024 + ln * 16) = rb8[ii];
    }
  };

  f32x4 acc[4][4];
  const f32x4 zf = {0.0f, 0.0f, 0.0f, 0.0f};
#pragma unroll
  for (int m = 0; m < 4; ++m)
#pragma unroll
    for (int n = 0; n < 4; ++n) acc[m][n] = zf;

  auto compute128 = [&](int slot) {
    const unsigned char* Ab = lds8 + slot * 65536;
    const unsigned char* Bb = Ab + 32768;
#pragma unroll
    for (int ks = 0; ks < 4; ++ks) {
      const int kb = ((ks >> 1) << 7) + ((kgrp + ((ks & 1) << 6)) ^ xm);
      f16x8 afr[4], bfr[4];
#pragma unroll
      for (int m = 0; m < 4; ++m)
        afr[m] = *(const f16x8*)(Ab + (wr * 64 + m * 16 + lanerow) * 256 + kb);
#pragma unroll
      for (int n = 0; n < 4; ++n)
        bfr[n] = *(const f16x8*)(Bb + (wc * 64 + n * 16 + lanerow) * 256 + kb);
      __builtin_amdgcn_s_setprio(1);
#pragma unroll
      for (int m = 0; m < 4; ++m)
#pragma unroll
        for (int n = 0; n < 4; ++n)
          acc[m][n] = __builtin_amdgcn_mfma_f32_16x16x32_f16(afr[m], bfr[n], acc[m][n], 0, 0, 0);
      __builtin_amdgcn_s_setprio(0);
    }
  };

  // ---- prologue: build/stage t0, publish ----
  if (!L) {
    if (tid < 128) {
      const int row = row0 + tid;
      float y0;
      if (t == 0) {
        y0 = inpy[row];
      } else {
        y0 = bout[0];
        const float* yp = ypartT + row;
#pragma unroll
        for (int nb2 = 0; nb2 < 32; ++nb2) y0 += yp[nb2 << 10];
      }
      const float* fsrc = ff + ((size_t)row * NT + t) * NDFF;
      f16x8 xv;
      xv[0] = (f16)y0;
#pragma unroll
      for (int jj = 0; jj < 7; ++jj) xv[1 + jj] = (f16)fsrc[jj];
      *(f16x8*)(lds8 + XAOFF + tid * 128 + ((tid & 7) << 4)) = xv;
    }
    f16x8 zv;
#pragma unroll
    for (int jj = 0; jj < 8; ++jj) zv[jj] = (f16)0.0f;
    for (int idx = tid; idx < 128 * 7; idx += 256) {
      const int r = idx / 7;
      const int ch = 1 + (idx - r * 7);
      *(f16x8*)(lds8 + XAOFF + r * 128 + ((ch ^ (r & 7)) << 4)) = zv;
    }
    if (t > 0 && cb < NQ && tid < 128) {   // emit y[t-1]
      const int row = row0 + tid;
      float s = bout[cb];
      const float* yp = ypartT + ((size_t)(cb << 5) << 10) + row;
#pragma unroll
      for (int nb2 = 0; nb2 < 32; ++nb2) s += yp[nb2 << 10];
      dout[(size_t)row * OUTSTRIDE + (t - 1) * NQ + cb] = s;
    }
    // stage t0 B (64k: 4 gll/wave, 128B rows) into slot0 B-region
#pragma unroll
    for (int ii = 0; ii < 4; ++ii) {
      const int ci = wv * 4 + ii;
      gll(Wp + (size_t)(cb * 128 + ci * 8 + (ln >> 3)) * KDIM + (ln & 7) * 8,
          lds8 + 32768 + ci * 1024);
    }
  } else {
    loadRegs(0);
    writeLDS(0);
  }
  asm volatile("s_waitcnt vmcnt(0) lgkmcnt(0)" ::: "memory");
  __builtin_amdgcn_s_barrier();      // t0 (+x) published to all waves

  // ---- main K loop: issue loads(i+1) -> compute(i) -> ds_write(i+1) -> bar --
#pragma unroll 1
  for (int i = 0; i < NTILE; ++i) {
    __builtin_amdgcn_sched_barrier(0);
    if (i + 1 < NTILE) loadRegs(i + 1);
    __builtin_amdgcn_sched_barrier(0);
    if (!L && i == 0) {
      // 64k x-tile: A from xA region (128B rows), B from slot0 (128B rows)
      const unsigned char* Ab = lds8 + XAOFF;
      const unsigned char* Bb = lds8 + 32768;
#pragma unroll
      for (int ks = 0; ks < 2; ++ks) {
        const int kb = (kgrp + (ks << 6)) ^ xm;
        f16x8 afr[4], bfr[4];
#pragma unroll
        for (int m = 0; m < 4; ++m)
          afr[m] = *(const f16x8*)(Ab + (wr * 64 + m * 16 + lanerow) * 128 + kb);
#pragma unroll
        for (int n = 0; n < 4; ++n)
          bfr[n] = *(const f16x8*)(Bb + (wc * 64 + n * 16 + lanerow) * 128 + kb);
        __builtin_amdgcn_s_setprio(1);
#pragma unroll
        for (int m = 0; m < 4; ++m)
#pragma unroll
          for (int n = 0; n < 4; ++n)
            acc[m][n] = __builtin_amdgcn_mfma_f32_16x16x32_f16(afr[m], bfr[n], acc[m][n], 0, 0, 0);
        __builtin_amdgcn_s_setprio(0);
      }
    } else {
      compute128(i & 1);
    }
    __builtin_amdgcn_sched_barrier(0);
    if (i + 1 < NTILE) writeLDS((i + 1) & 1);   // auto vmcnt waits on ra/rb
    asm volatile("s_waitcnt lgkmcnt(0)" ::: "memory");
    __builtin_amdgcn_s_barrier();   // publish t_{i+1}; free slot i&1
    __builtin_amdgcn_sched_barrier(0);
  }

  // ---- epilogue: cell update (register-local; n-frag == gate) ----
  // hbuf in the slot OPPOSITE the last tile; all waves are past the final
  // barrier, that slot's readers are done -> safe.
  float* hb = (float*)(lds8 + (L ? 0 : 65536));
  const float bi = bias[hcol];
  const float bf = bias[NH + hcol];
  const float bg = bias[2 * NH + hcol];
  const float bo = bias[3 * NH + hcol];
  const int cbase = ((rb * 32 + cb) * 4 + wv) * 1024;
#pragma unroll
  for (int m = 0; m < 4; ++m) {
    const f32x4 vi = acc[m][0], vf = acc[m][1], vg = acc[m][2], vo = acc[m][3];
#pragma unroll
    for (int r = 0; r < 4; ++r) {
      const int j = m * 4 + r;
      const int rloc = wr * 64 + m * 16 + ((ln >> 4) << 2) + r;
      const float c_old = cpk[cbase + j * 64 + ln];
      const float ig = sigf(vi[r] + bi);
      const float fg = sigf(vf[r] + bf);
      const float gg = tanhfast(vg[r] + bg);
      const float og = sigf(vo[r] + bo);
      const float cn = fg * c_old + ig * gg;
      cpk[cbase + j * 64 + ln] = cn;
      hb[rloc * 36 + wc * 16 + lanerow] = og * tanhfast(cn);
    }
  }
  asm volatile("s_waitcnt lgkmcnt(0)" ::: "memory");
  __builtin_amdgcn_s_barrier();
  // wide h store: 2 units/thread, each = 8 cols of one row, 16B coalesced
#pragma unroll
  for (int u2 = 0; u2 < 2; ++u2) {
    const int unit = tid * 2 + u2;          // 0..511
    const int r = unit >> 2;
    const int u = unit & 3;
    const f32x4 lo = *(const f32x4*)(hb + r * 36 + u * 8);
    const f32x4 hi = *(const f32x4*)(hb + r * 36 + u * 8 + 4);
    f16x8 v;
#pragma unroll
    for (int jj = 0; jj < 4; ++jj) { v[jj] = (f16)lo[jj]; v[4 + jj] = (f16)hi[jj]; }
    const int rowg = row0 + r;
    const int pb = ((hcol0 & 63) << 1) + u * 16;
    *(f16x8*)((unsigned char*)hout + (size_t)rowg * 2048 + ((hcol0 >> 6) << 7) +
              (pb ^ ((rowg & 7) << 4))) = v;
  }
  if (L) {
    // y partials over this block's 32 h-cols: ypartT[q][cb][row]
    for (int task = tid; task < 128 * NQ; task += 256) {
      const int rloc = task & 127;
      const int q = task >> 7;
      const float* wq = Wout + q * NH + hcol0;
      float s = 0.0f;
#pragma unroll
      for (int c2 = 0; c2 < 32; ++c2) s += hb[rloc * 36 + c2] * wq[c2];
      ypartT[(size_t)((q << 5) + cb) * 1024 + row0 + rloc] = s;
    }
  }
}

// ---------------------------------------------------------------------------
extern "C" void kernel_launch(void* const* d_in, const int* in_sizes, int n_in,
                              void* d_out, int out_size, void* d_ws, size_t ws_size,
                              hipStream_t stream) {
  const float* inpy = (const float*)d_in[2];
  const float* h_in = (const float*)d_in[3];
  const float* c_in = (const float*)d_in[4];
  const float* ff   = (const float*)d_in[5];
  const float* Wih0 = (const float*)d_in[9];
  const float* Whh0 = (const float*)d_in[10];
  const float* bih0 = (const float*)d_in[11];
  const float* bhh0 = (const float*)d_in[12];
  const float* Wih1 = (const float*)d_in[13];
  const float* Whh1 = (const float*)d_in[14];
  const float* bih1 = (const float*)d_in[15];
  const float* bhh1 = (const float*)d_in[16];
  const float* Wout = (const float*)d_in[17];
  const float* bout = (const float*)d_in[18];
  float* dout = (float*)d_out;

  unsigned char* ws = (unsigned char*)d_ws;
  size_t off = 0;
  auto alloc = [&](size_t bytes) -> void* {
    void* p = ws + off;
    off += (bytes + 255) & ~(size_t)255;
    return p;
  };
  f16* Wp0 = (f16*)alloc((size_t)4096 * K0 * 2);
  f16* Wp1 = (f16*)alloc((size_t)4096 * K1 * 2);
  f16* h0b0 = (f16*)alloc((size_t)NBATCH * NH * 2);
  f16* h0b1 = (f16*)alloc((size_t)NBATCH * NH * 2);
  f16* h1b0 = (f16*)alloc((size_t)NBATCH * NH * 2);
  f16* h1b1 = (f16*)alloc((size_t)NBATCH * NH * 2);
  float* bias0 = (float*)alloc(4096 * 4);
  float* bias1 = (float*)alloc(4096 * 4);
  float* ypartT = (float*)alloc((size_t)NQ * 32 * 1024 * 4);
  float* c0p = (float*)alloc((size_t)NBATCH * NH * 4);
  float* c1p = (float*)alloc((size_t)NBATCH * NH * 4);
  f16* h0b[2] = {h0b0, h0b1};
  f16* h1b[2] = {h1b0, h1b1};

  pack_w0<<<(4096 * K0) / 256, 256, 0, stream>>>(Wih0, Whh0, Wp0);
  pack_w1<<<(4096 * K1) / 256, 256, 0, stream>>>(Wih1, Whh1, Wp1);
  pack_bias<<<16, 256, 0, stream>>>(bih0, bhh0, bih1, bhh1, bias0, bias1);
  init_h<<<(2 * NBATCH * NH) / 256, 256, 0, stream>>>(h_in, h0b0, h1b0);
  init_c<<<(2 * NBATCH * NH) / 256, 256, 0, stream>>>(c_in, c0p, c1p);

  for (int t = 0; t < NT; ++t) {
    const int p = t & 1;
    // layer 0: A = [x | h0prev], writes h0new; also y[t-1] output + feedback
    step_kernel<0><<<256, 256, 0, stream>>>(Wp0, bias0, h0b[p], nullptr, h0b[1 - p],
                                            c0p, ff, inpy, ypartT, nullptr, bout, dout, t);
    // layer 1: A = [h0new | h1prev], writes h1new + y partials
    step_kernel<1><<<256, 256, 0, stream>>>(Wp1, bias1, h0b[1 - p], h1b[p], h1b[1 - p],
                                            c1p, nullptr, nullptr, ypartT, Wout, bout, dout, t);
  }
  final_y<<<36, 256, 0, stream>>>(ypartT, bout, dout);
}